// Round 1
// baseline (847.904 us; speedup 1.0000x reference)
//
#include <hip/hip_runtime.h>
#include <hip/hip_bf16.h>

// ---------------------------------------------------------------------------
// MoE transformer block, MI355X gfx950.
// B=8 S=512 D=768 H=12 dh=64 E=14 K=4 HID=1536 SH=3072
// Key insight: reference computes all 14 experts densely but weights are zero
// off the top-4 -> compute only top-4 experts per batch (77 GF vs 270 GF).
// All GEMMs: f16 MFMA 16x16x32, 128x128 tile, fp32 accumulate.
// Router path kept in full fp32 so expert selection matches reference exactly.
// ---------------------------------------------------------------------------

typedef _Float16 f16x8 __attribute__((ext_vector_type(8)));
typedef float f32x4 __attribute__((ext_vector_type(4)));
typedef _Float16 f16;

__device__ __forceinline__ float gelu_exact(float x) {
  return 0.5f * x * (1.0f + erff(x * 0.70710678118654752f));
}

__device__ __forceinline__ f32x4 mfma16(f16x8 a, f16x8 b, f32x4 c) {
  return __builtin_amdgcn_mfma_f32_16x16x32_f16(a, b, c, 0, 0, 0);
}

// ---------------------------------------------------------------------------
// LayerNorm: fp32 in -> f16 out, saves per-row mean and rstd (for router).
// One block per row, 256 threads, D=768 (3 elems/thread).
// ---------------------------------------------------------------------------
__global__ __launch_bounds__(256) void ln_kernel(
    const float* __restrict__ x, const float* __restrict__ g,
    const float* __restrict__ bt, f16* __restrict__ out,
    float* __restrict__ mout, float* __restrict__ rout)
{
  const int row = blockIdx.x;
  const float* xr = x + (long)row * 768;
  const int t = threadIdx.x;
  float v0 = xr[t], v1 = xr[t + 256], v2 = xr[t + 512];
  __shared__ float sb[8];
  float s = v0 + v1 + v2;
  #pragma unroll
  for (int o = 32; o > 0; o >>= 1) s += __shfl_xor(s, o, 64);
  const int w = t >> 6;
  if ((t & 63) == 0) sb[w] = s;
  __syncthreads();
  const float mean = (sb[0] + sb[1] + sb[2] + sb[3]) * (1.0f / 768.0f);
  const float d0 = v0 - mean, d1 = v1 - mean, d2 = v2 - mean;
  float q = d0 * d0 + d1 * d1 + d2 * d2;
  #pragma unroll
  for (int o = 32; o > 0; o >>= 1) q += __shfl_xor(q, o, 64);
  if ((t & 63) == 0) sb[4 + w] = q;
  __syncthreads();
  const float var = (sb[4] + sb[5] + sb[6] + sb[7]) * (1.0f / 768.0f);
  const float rstd = rsqrtf(var + 1e-5f);
  f16* orow = out + (long)row * 768;
  orow[t]       = (f16)(d0 * rstd * g[t]       + bt[t]);
  orow[t + 256] = (f16)(d1 * rstd * g[t + 256] + bt[t + 256]);
  orow[t + 512] = (f16)(d2 * rstd * g[t + 512] + bt[t + 512]);
  if (t == 0) { mout[row] = mean; rout[row] = rstd; }
}

// ---------------------------------------------------------------------------
// Transpose + fp32->f16: in [rows][cols] fp32 -> out [cols][rows] f16.
// 32x32 LDS tiles, blockIdx.z batches (experts).
// ---------------------------------------------------------------------------
__global__ __launch_bounds__(256) void transpose_f16(
    const float* __restrict__ in, f16* __restrict__ out, int rows, int cols)
{
  __shared__ float tile[32][33];
  const long boff = (long)blockIdx.z * rows * cols;
  const float* inb = in + boff;
  f16* outb = out + boff;
  const int c0 = blockIdx.x * 32, r0 = blockIdx.y * 32;
  const int tx = threadIdx.x & 31, ty = threadIdx.x >> 5;
  #pragma unroll
  for (int i = 0; i < 32; i += 8)
    tile[ty + i][tx] = inb[(long)(r0 + ty + i) * cols + c0 + tx];
  __syncthreads();
  #pragma unroll
  for (int i = 0; i < 32; i += 8)
    outb[(long)(c0 + ty + i) * rows + r0 + tx] = (f16)tile[tx][ty + i];
}

// ---------------------------------------------------------------------------
// Generic GEMM: C[M,N] = A[M,K] @ W^T   (A f16 row-major, W f16 [N][K]).
// 128x128 tile, BK=32, 256 threads = 4 waves each 64x64 (4x4 MFMA tiles).
// Batched via blockIdx.z (expert pairs); expert index read from topkIdx.
// ---------------------------------------------------------------------------
#define EPI_QKV   0
#define EPI_RESID 1
#define EPI_GELU  2
#define EPI_PLAIN 3

template <int EPI>
__global__ __launch_bounds__(256) void gemm_bt(
    const f16* __restrict__ A, int K, long strideA, int aShift,
    const f16* __restrict__ W, long strideW,
    const float* __restrict__ bias, int strideBias,
    const int* __restrict__ topkIdx,
    void* __restrict__ outv, long strideOut, int ldout,
    const float* __restrict__ resid)
{
  __shared__ f16 sA[128 * 32];
  __shared__ f16 sB[128 * 32];
  const int tid = threadIdx.x;
  const int pair = blockIdx.z;
  const int m0 = blockIdx.y * 128;
  const int n0 = blockIdx.x * 128;
  const f16* Ab = A + ((long)(pair >> aShift)) * strideA;
  const int wsel = topkIdx ? topkIdx[pair] : pair;
  const f16* Wb = W + (long)wsel * strideW;

  const int f = tid * 8;          // staging: each thread moves 2x 16B chunks
  const int fr = f >> 5;          // tile row 0..63
  const int fc = f & 31;          // tile col (k)
  const int lane = tid & 63, wid = tid >> 6;
  const int wm = (wid >> 1) * 64, wn = (wid & 1) * 64;
  const int lr = lane & 15, q4 = lane >> 4;

  f32x4 zero = {0.f, 0.f, 0.f, 0.f};
  f32x4 acc[4][4];
  #pragma unroll
  for (int i = 0; i < 4; i++)
    #pragma unroll
    for (int j = 0; j < 4; j++) acc[i][j] = zero;

  for (int k0 = 0; k0 < K; k0 += 32) {
    __syncthreads();
    *(f16x8*)&sA[f]        = *(const f16x8*)&Ab[(long)(m0 + fr) * K + k0 + fc];
    *(f16x8*)&sA[f + 2048] = *(const f16x8*)&Ab[(long)(m0 + fr + 64) * K + k0 + fc];
    *(f16x8*)&sB[f]        = *(const f16x8*)&Wb[(long)(n0 + fr) * K + k0 + fc];
    *(f16x8*)&sB[f + 2048] = *(const f16x8*)&Wb[(long)(n0 + fr + 64) * K + k0 + fc];
    __syncthreads();
    f16x8 av[4], bv[4];
    #pragma unroll
    for (int i = 0; i < 4; i++) av[i] = *(const f16x8*)&sA[(wm + i * 16 + lr) * 32 + q4 * 8];
    #pragma unroll
    for (int j = 0; j < 4; j++) bv[j] = *(const f16x8*)&sB[(wn + j * 16 + lr) * 32 + q4 * 8];
    #pragma unroll
    for (int i = 0; i < 4; i++)
      #pragma unroll
      for (int j = 0; j < 4; j++) acc[i][j] = mfma16(av[i], bv[j], acc[i][j]);
  }

  // Epilogue. C/D layout: col = lane&15, row = (lane>>4)*4 + reg.
  #pragma unroll
  for (int i = 0; i < 4; i++) {
    #pragma unroll
    for (int j = 0; j < 4; j++) {
      #pragma unroll
      for (int r = 0; r < 4; r++) {
        const int row = m0 + wm + i * 16 + q4 * 4 + r;
        const int col = n0 + wn + j * 16 + lr;
        float v = acc[i][j][r];
        if constexpr (EPI == EPI_QKV) {
          // col in [0,2304): i3 = col/768, head = (col%768)/64, d = col%64
          f16* qb = (f16*)outv;
          const int i3 = col / 768;
          const int rem = col - i3 * 768;
          const int hh = rem >> 6, dd = rem & 63;
          const int bb = row >> 9, ss = row & 511;
          const long bh = bb * 12 + hh;
          if (i3 == 0)      qb[(bh * 512 + ss) * 64 + dd] = (f16)v;                 // Q [bh][s][d]
          else if (i3 == 1) qb[3145728 + (bh * 512 + ss) * 64 + dd] = (f16)v;       // K [bh][s][d]
          else              qb[6291456 + (bh * 64 + dd) * 512 + ss] = (f16)v;       // V^T [bh][d][s]
        } else if constexpr (EPI == EPI_RESID) {
          float* ob = (float*)outv;
          v += bias[col];
          ob[(long)row * ldout + col] = resid[(long)row * ldout + col] + v;
        } else if constexpr (EPI == EPI_GELU) {
          f16* ob = (f16*)outv + (long)pair * strideOut;
          v += bias[(long)wsel * strideBias + col];
          ob[(long)row * ldout + col] = (f16)gelu_exact(v);
        } else {
          f16* ob = (f16*)outv + (long)pair * strideOut;
          v += bias[(long)wsel * strideBias + col];
          ob[(long)row * ldout + col] = (f16)v;
        }
      }
    }
  }
}

// ---------------------------------------------------------------------------
// Fused attention per (b*h, q-tile of 64): QK^T in regs, softmax via 16-lane
// shuffles (each wave owns 16 whole q-rows), P -> global f16, then P@V.
// ---------------------------------------------------------------------------
__global__ __launch_bounds__(256) void attn_kernel(
    const f16* __restrict__ Q, const f16* __restrict__ Kt,
    const f16* __restrict__ Vt, f16* __restrict__ P, f16* __restrict__ AO)
{
  const int bh = blockIdx.x;           // 96
  const int qt = blockIdx.y;           // 8
  const int t = threadIdx.x;
  const int lane = t & 63, w = t >> 6;
  const int lr = lane & 15, q4 = lane >> 4;
  const int r0 = qt * 64 + w * 16;     // wave owns q-rows r0..r0+15
  const f16* Qh = Q + (long)bh * 512 * 64;
  const f16* Kh = Kt + (long)bh * 512 * 64;

  f32x4 zero = {0.f, 0.f, 0.f, 0.f};
  f32x4 acc[32];
  #pragma unroll
  for (int i = 0; i < 32; i++) acc[i] = zero;

  #pragma unroll
  for (int kk = 0; kk < 2; kk++) {
    f16x8 a = *(const f16x8*)&Qh[(r0 + lr) * 64 + kk * 32 + q4 * 8];
    #pragma unroll
    for (int nt = 0; nt < 32; nt++) {
      f16x8 b = *(const f16x8*)&Kh[(nt * 16 + lr) * 64 + kk * 32 + q4 * 8];
      acc[nt] = mfma16(a, b, acc[nt]);
    }
  }

  const float cscale = 0.125f * 1.44269504089f;  // scale * log2(e)
  f16* Ph = P + (long)bh * 512 * 512;
  #pragma unroll
  for (int r = 0; r < 4; r++) {
    float m = -1e30f;
    #pragma unroll
    for (int nt = 0; nt < 32; nt++) m = fmaxf(m, acc[nt][r]);
    #pragma unroll
    for (int o = 1; o < 16; o <<= 1) m = fmaxf(m, __shfl_xor(m, o, 64));
    float s = 0.f;
    #pragma unroll
    for (int nt = 0; nt < 32; nt++) {
      float e = exp2f((acc[nt][r] - m) * cscale);
      acc[nt][r] = e; s += e;
    }
    #pragma unroll
    for (int o = 1; o < 16; o <<= 1) s += __shfl_xor(s, o, 64);
    const float inv = 1.f / s;
    const int rowg = r0 + q4 * 4 + r;
    #pragma unroll
    for (int nt = 0; nt < 32; nt++)
      Ph[(long)rowg * 512 + nt * 16 + lr] = (f16)(acc[nt][r] * inv);
  }
  __syncthreads();  // waves read back only rows they wrote (vmcnt drain)

  const f16* Vh = Vt + (long)bh * 64 * 512;
  f32x4 o4[4];
  #pragma unroll
  for (int i = 0; i < 4; i++) o4[i] = zero;
  #pragma unroll
  for (int kk = 0; kk < 16; kk++) {
    f16x8 a = *(const f16x8*)&Ph[(r0 + lr) * 512 + kk * 32 + q4 * 8];
    #pragma unroll
    for (int nt = 0; nt < 4; nt++) {
      f16x8 b = *(const f16x8*)&Vh[(nt * 16 + lr) * 512 + kk * 32 + q4 * 8];
      o4[nt] = mfma16(a, b, o4[nt]);
    }
  }
  const int b_ = bh / 12, h_ = bh - b_ * 12;
  #pragma unroll
  for (int nt = 0; nt < 4; nt++)
    #pragma unroll
    for (int r = 0; r < 4; r++) {
      const int rowg = r0 + q4 * 4 + r;
      AO[((long)(b_ * 512 + rowg)) * 768 + h_ * 64 + nt * 16 + lr] = (f16)o4[nt][r];
    }
}

// ---------------------------------------------------------------------------
// Router: fp32 end-to-end (selection must match reference).
// One block per batch. seq_repr from x2 + saved LN stats; 2-layer MLP;
// softmax -> top4 -> softmax(top4 probs) -> wslot/topk.
// ---------------------------------------------------------------------------
__global__ __launch_bounds__(256) void router_kernel(
    const float* __restrict__ x2, const float* __restrict__ lnm,
    const float* __restrict__ lnr, const float* __restrict__ g2,
    const float* __restrict__ b2ln, const float* __restrict__ rw1,
    const float* __restrict__ rb1, const float* __restrict__ rw2,
    const float* __restrict__ rb2, float* __restrict__ wslot,
    int* __restrict__ topkIdx)
{
  __shared__ float seq[768];
  __shared__ float g1[768];
  __shared__ float lg[14];
  const int b = blockIdx.x, t = threadIdx.x;
  float a0 = 0.f, a1 = 0.f, a2 = 0.f;
  for (int s = 0; s < 512; s++) {
    const long base = (long)b * 512 + s;
    const float m = lnm[base], r = lnr[base];
    const float* xr = x2 + base * 768;
    a0 += (xr[t] - m) * r;
    a1 += (xr[t + 256] - m) * r;
    a2 += (xr[t + 512] - m) * r;
  }
  seq[t]       = a0 * (1.f / 512.f) * g2[t]       + b2ln[t];
  seq[t + 256] = a1 * (1.f / 512.f) * g2[t + 256] + b2ln[t + 256];
  seq[t + 512] = a2 * (1.f / 512.f) * g2[t + 512] + b2ln[t + 512];
  __syncthreads();
  #pragma unroll
  for (int i = 0; i < 3; i++) {
    const int j = t + 256 * i;
    float a = rb1[j];
    for (int d = 0; d < 768; d++) a += seq[d] * rw1[(long)d * 768 + j];
    g1[j] = gelu_exact(a);
  }
  __syncthreads();
  if (t < 14) {
    float a = rb2[t];
    for (int d = 0; d < 768; d++) a += g1[d] * rw2[d * 14 + t];
    lg[t] = a;
  }
  __syncthreads();
  if (t == 0) {
    float mx = -1e30f;
    for (int e = 0; e < 14; e++) mx = fmaxf(mx, lg[e]);
    float p[14], s = 0.f;
    for (int e = 0; e < 14; e++) { p[e] = expf(lg[e] - mx); s += p[e]; }
    for (int e = 0; e < 14; e++) p[e] /= s;
    int idx[4]; float val[4]; bool used[14];
    for (int e = 0; e < 14; e++) used[e] = false;
    for (int k = 0; k < 4; k++) {
      int best = -1; float bv = -1.f;
      for (int e = 0; e < 14; e++)
        if (!used[e] && p[e] > bv) { bv = p[e]; best = e; }
      used[best] = true; idx[k] = best; val[k] = bv;
    }
    const float m2 = val[0];
    float ss = 0.f, e4[4];
    for (int k = 0; k < 4; k++) { e4[k] = expf(val[k] - m2); ss += e4[k]; }
    for (int k = 0; k < 4; k++) {
      wslot[b * 4 + k] = e4[k] / ss;
      topkIdx[b * 4 + k] = idx[k];
    }
  }
}

// ---------------------------------------------------------------------------
// Final combine: out = x2 + sum_k w[b,k]*eo[b,k] + shared_out
// ---------------------------------------------------------------------------
__global__ __launch_bounds__(256) void combine_kernel(
    const float* __restrict__ x2, const f16* __restrict__ shout,
    const f16* __restrict__ eo, const float* __restrict__ wslot,
    float* __restrict__ out)
{
  const long i = (long)blockIdx.x * 256 + threadIdx.x;
  const long b = i / (512L * 768);
  const long loc = i - b * (512L * 768);
  float v = x2[i] + (float)shout[i];
  #pragma unroll
  for (int k = 0; k < 4; k++)
    v += wslot[b * 4 + k] * (float)eo[(b * 4 + k) * (512L * 768) + loc];
  out[i] = v;
}

// ---------------------------------------------------------------------------
// Workspace layout (bytes). Phase A (attention) and Phase B (MoE) overlap.
// Total footprint ~177 MB.
// ---------------------------------------------------------------------------
static const long OFF_X2    = 0L;                       // 12582912 fp32 x2
static const long OFF_LNM   = 12582912L;                // 16384
static const long OFF_LNR   = OFF_LNM + 16384L;         // 16384
static const long OFF_WSLOT = OFF_LNR + 16384L;         // 128 (+pad)
static const long OFF_TOPK  = OFF_WSLOT + 256L;         // 128 (+pad)
static const long OFF_A     = 13631488L;                // phase region base
// Phase A
static const long A_H1     = OFF_A;                     // 6291456
static const long A_QKVWT  = A_H1 + 6291456L;           // 3538944
static const long A_Q      = A_QKVWT + 3538944L;        // 6291456 (Q,K,Vt contiguous)
static const long A_P      = A_Q + 3L * 6291456L;       // 50331648
static const long A_AO     = A_P + 50331648L;           // 6291456
static const long A_PROJWT = A_AO + 6291456L;           // 1179648
// Phase B (aliases phase A region)
static const long B_H      = OFF_A;                     // 6291456
static const long B_EW1T   = B_H + 6291456L;            // 33030144
static const long B_EW2T   = B_EW1T + 33030144L;        // 33030144
static const long B_HID    = B_EW2T + 33030144L;        // 50331648
static const long B_EO     = B_HID + 50331648L;         // 25165824
static const long B_SHW1T  = B_EO + 25165824L;          // 4718592
static const long B_SHW2T  = B_SHW1T + 4718592L;        // 4718592
static const long B_SHOUT  = B_SHW2T + 4718592L;        // 6291456
static const long B_SHID   = B_EW1T;                    // reuse after expert1 (25165824 <= 33030144)

extern "C" void kernel_launch(void* const* d_in, const int* in_sizes, int n_in,
                              void* d_out, int out_size, void* d_ws, size_t ws_size,
                              hipStream_t stream) {
  const float* x     = (const float*)d_in[0];
  const float* ln1g  = (const float*)d_in[1];
  const float* ln1b  = (const float*)d_in[2];
  const float* qkvw  = (const float*)d_in[3];
  const float* projw = (const float*)d_in[4];
  const float* projb = (const float*)d_in[5];
  const float* ln2g  = (const float*)d_in[6];
  const float* ln2b  = (const float*)d_in[7];
  const float* rw1   = (const float*)d_in[8];
  const float* rb1   = (const float*)d_in[9];
  const float* rw2   = (const float*)d_in[10];
  const float* rb2   = (const float*)d_in[11];
  const float* ew1   = (const float*)d_in[12];
  const float* eb1   = (const float*)d_in[13];
  const float* ew2   = (const float*)d_in[14];
  const float* eb2   = (const float*)d_in[15];
  const float* shw1  = (const float*)d_in[16];
  const float* shb1  = (const float*)d_in[17];
  const float* shw2  = (const float*)d_in[18];
  const float* shb2  = (const float*)d_in[19];

  char* ws = (char*)d_ws;
  float* x2    = (float*)(ws + OFF_X2);
  float* lnm   = (float*)(ws + OFF_LNM);
  float* lnr   = (float*)(ws + OFF_LNR);
  float* wslot = (float*)(ws + OFF_WSLOT);
  int*   topk  = (int*)(ws + OFF_TOPK);
  f16* h1     = (f16*)(ws + A_H1);
  f16* qkvwt  = (f16*)(ws + A_QKVWT);
  f16* Qb     = (f16*)(ws + A_Q);
  f16* Kb     = Qb + 3145728;
  f16* Vtb    = Qb + 6291456;
  f16* Pb     = (f16*)(ws + A_P);
  f16* aob    = (f16*)(ws + A_AO);
  f16* projwt = (f16*)(ws + A_PROJWT);
  f16* hbuf   = (f16*)(ws + B_H);
  f16* ew1t   = (f16*)(ws + B_EW1T);
  f16* ew2t   = (f16*)(ws + B_EW2T);
  f16* hid    = (f16*)(ws + B_HID);
  f16* eo     = (f16*)(ws + B_EO);
  f16* shw1t  = (f16*)(ws + B_SHW1T);
  f16* shw2t  = (f16*)(ws + B_SHW2T);
  f16* shout  = (f16*)(ws + B_SHOUT);
  f16* shid   = (f16*)(ws + B_SHID);

  // ---- Phase A: attention ----
  transpose_f16<<<dim3(72, 24, 1), 256, 0, stream>>>(qkvw, qkvwt, 768, 2304);
  transpose_f16<<<dim3(24, 24, 1), 256, 0, stream>>>(projw, projwt, 768, 768);
  ln_kernel<<<4096, 256, 0, stream>>>(x, ln1g, ln1b, h1, lnm, lnr);
  gemm_bt<EPI_QKV><<<dim3(18, 32, 1), 256, 0, stream>>>(
      h1, 768, 0, 0, qkvwt, 0, nullptr, 0, nullptr, (void*)Qb, 0, 0, nullptr);
  attn_kernel<<<dim3(96, 8, 1), 256, 0, stream>>>(Qb, Kb, Vtb, Pb, aob);
  gemm_bt<EPI_RESID><<<dim3(6, 32, 1), 256, 0, stream>>>(
      aob, 768, 0, 0, projwt, 0, projb, 0, nullptr, (void*)x2, 0, 768, x);

  // ---- Phase B: MoE ----
  ln_kernel<<<4096, 256, 0, stream>>>(x2, ln2g, ln2b, hbuf, lnm, lnr);
  router_kernel<<<8, 256, 0, stream>>>(x2, lnm, lnr, ln2g, ln2b,
                                       rw1, rb1, rw2, rb2, wslot, topk);
  transpose_f16<<<dim3(48, 24, 14), 256, 0, stream>>>(ew1, ew1t, 768, 1536);
  transpose_f16<<<dim3(24, 48, 14), 256, 0, stream>>>(ew2, ew2t, 1536, 768);
  transpose_f16<<<dim3(96, 24, 1), 256, 0, stream>>>(shw1, shw1t, 768, 3072);
  transpose_f16<<<dim3(24, 96, 1), 256, 0, stream>>>(shw2, shw2t, 3072, 768);
  // expert ffn1: per pair (b,slot): hid = gelu(h[b] @ w1[e]^T + b1[e])
  gemm_bt<EPI_GELU><<<dim3(12, 4, 32), 256, 0, stream>>>(
      hbuf, 768, 512L * 768, 2, ew1t, 1536L * 768, eb1, 1536, topk,
      (void*)hid, 512L * 1536, 1536, nullptr);
  // expert ffn2: eo = hid @ w2[e]^T + b2[e]
  gemm_bt<EPI_PLAIN><<<dim3(6, 4, 32), 256, 0, stream>>>(
      hid, 1536, 512L * 1536, 0, ew2t, 768L * 1536, eb2, 768, topk,
      (void*)eo, 512L * 768, 768, nullptr);
  // shared expert
  gemm_bt<EPI_GELU><<<dim3(24, 32, 1), 256, 0, stream>>>(
      hbuf, 768, 0, 0, shw1t, 0, shb1, 0, nullptr, (void*)shid, 0, 3072, nullptr);
  gemm_bt<EPI_PLAIN><<<dim3(6, 32, 1), 256, 0, stream>>>(
      shid, 3072, 0, 0, shw2t, 0, shb2, 0, nullptr, (void*)shout, 0, 768, nullptr);

  combine_kernel<<<12288, 256, 0, stream>>>(x2, shout, eo, wslot, (float*)d_out);
}

// Round 2
// 765.942 us; speedup vs baseline: 1.1070x; 1.1070x over previous
//
#include <hip/hip_runtime.h>
#include <hip/hip_bf16.h>

// ---------------------------------------------------------------------------
// MoE transformer block, MI355X gfx950.
// B=8 S=512 D=768 H=12 dh=64 E=14 K=4 HID=1536 SH=3072
// R2: (1) router seq-mean parallelized (was 179us latency-bound serial loop);
//     (2) GEMM staging via global_load_lds width=16 (m97 pattern).
// ---------------------------------------------------------------------------

typedef _Float16 f16x8 __attribute__((ext_vector_type(8)));
typedef float f32x4 __attribute__((ext_vector_type(4)));
typedef _Float16 f16;

__device__ __forceinline__ float gelu_exact(float x) {
  return 0.5f * x * (1.0f + erff(x * 0.70710678118654752f));
}

__device__ __forceinline__ f32x4 mfma16(f16x8 a, f16x8 b, f32x4 c) {
  return __builtin_amdgcn_mfma_f32_16x16x32_f16(a, b, c, 0, 0, 0);
}

// async global->LDS, 16B per lane; LDS dst must be wave-uniform base + lane*16
#define ASYNC_CP16(g, l)                                            \
  __builtin_amdgcn_global_load_lds(                                 \
      (const __attribute__((address_space(1))) void*)(g),           \
      (__attribute__((address_space(3))) void*)(l), 16, 0, 0)

// ---------------------------------------------------------------------------
// LayerNorm: fp32 in -> f16 out, saves per-row mean and rstd (for router).
// ---------------------------------------------------------------------------
__global__ __launch_bounds__(256) void ln_kernel(
    const float* __restrict__ x, const float* __restrict__ g,
    const float* __restrict__ bt, f16* __restrict__ out,
    float* __restrict__ mout, float* __restrict__ rout)
{
  const int row = blockIdx.x;
  const float* xr = x + (long)row * 768;
  const int t = threadIdx.x;
  float v0 = xr[t], v1 = xr[t + 256], v2 = xr[t + 512];
  __shared__ float sb[8];
  float s = v0 + v1 + v2;
  #pragma unroll
  for (int o = 32; o > 0; o >>= 1) s += __shfl_xor(s, o, 64);
  const int w = t >> 6;
  if ((t & 63) == 0) sb[w] = s;
  __syncthreads();
  const float mean = (sb[0] + sb[1] + sb[2] + sb[3]) * (1.0f / 768.0f);
  const float d0 = v0 - mean, d1 = v1 - mean, d2 = v2 - mean;
  float q = d0 * d0 + d1 * d1 + d2 * d2;
  #pragma unroll
  for (int o = 32; o > 0; o >>= 1) q += __shfl_xor(q, o, 64);
  if ((t & 63) == 0) sb[4 + w] = q;
  __syncthreads();
  const float var = (sb[4] + sb[5] + sb[6] + sb[7]) * (1.0f / 768.0f);
  const float rstd = rsqrtf(var + 1e-5f);
  f16* orow = out + (long)row * 768;
  orow[t]       = (f16)(d0 * rstd * g[t]       + bt[t]);
  orow[t + 256] = (f16)(d1 * rstd * g[t + 256] + bt[t + 256]);
  orow[t + 512] = (f16)(d2 * rstd * g[t + 512] + bt[t + 512]);
  if (t == 0) { mout[row] = mean; rout[row] = rstd; }
}

// ---------------------------------------------------------------------------
// Transpose + fp32->f16: in [rows][cols] fp32 -> out [cols][rows] f16.
// ---------------------------------------------------------------------------
__global__ __launch_bounds__(256) void transpose_f16(
    const float* __restrict__ in, f16* __restrict__ out, int rows, int cols)
{
  __shared__ float tile[32][33];
  const long boff = (long)blockIdx.z * rows * cols;
  const float* inb = in + boff;
  f16* outb = out + boff;
  const int c0 = blockIdx.x * 32, r0 = blockIdx.y * 32;
  const int tx = threadIdx.x & 31, ty = threadIdx.x >> 5;
  #pragma unroll
  for (int i = 0; i < 32; i += 8)
    tile[ty + i][tx] = inb[(long)(r0 + ty + i) * cols + c0 + tx];
  __syncthreads();
  #pragma unroll
  for (int i = 0; i < 32; i += 8)
    outb[(long)(c0 + ty + i) * rows + r0 + tx] = (f16)tile[tx][ty + i];
}

// ---------------------------------------------------------------------------
// Generic GEMM: C[M,N] = A[M,K] @ W^T   (A f16 row-major, W f16 [N][K]).
// 128x128 tile, BK=32, 4 waves x 64x64. Staging via global_load_lds (m97).
// ---------------------------------------------------------------------------
#define EPI_QKV   0
#define EPI_RESID 1
#define EPI_GELU  2
#define EPI_PLAIN 3

template <int EPI>
__global__ __launch_bounds__(256) void gemm_bt(
    const f16* __restrict__ A, int K, long strideA, int aShift,
    const f16* __restrict__ W, long strideW,
    const float* __restrict__ bias, int strideBias,
    const int* __restrict__ topkIdx,
    void* __restrict__ outv, long strideOut, int ldout,
    const float* __restrict__ resid)
{
  __shared__ f16 sA[128 * 32];
  __shared__ f16 sB[128 * 32];
  const int tid = threadIdx.x;
  const int pair = blockIdx.z;
  const int m0 = blockIdx.y * 128;
  const int n0 = blockIdx.x * 128;
  const f16* Ab = A + ((long)(pair >> aShift)) * strideA;
  const int wsel = topkIdx ? topkIdx[pair] : pair;
  const f16* Wb = W + (long)wsel * strideW;

  const int f = tid * 8;          // each lane: 16B chunks, LDS off = tid*16
  const int fr = f >> 5;          // tile row 0..63
  const int fc = f & 31;          // tile col (k)
  const int lane = tid & 63, wid = tid >> 6;
  const int wm = (wid >> 1) * 64, wn = (wid & 1) * 64;
  const int lr = lane & 15, q4 = lane >> 4;

  f32x4 zero = {0.f, 0.f, 0.f, 0.f};
  f32x4 acc[4][4];
  #pragma unroll
  for (int i = 0; i < 4; i++)
    #pragma unroll
    for (int j = 0; j < 4; j++) acc[i][j] = zero;

  for (int k0 = 0; k0 < K; k0 += 32) {
    __syncthreads();
    ASYNC_CP16(&Ab[(long)(m0 + fr) * K + k0 + fc],      &sA[f]);
    ASYNC_CP16(&Ab[(long)(m0 + fr + 64) * K + k0 + fc], &sA[f + 2048]);
    ASYNC_CP16(&Wb[(long)(n0 + fr) * K + k0 + fc],      &sB[f]);
    ASYNC_CP16(&Wb[(long)(n0 + fr + 64) * K + k0 + fc], &sB[f + 2048]);
    __syncthreads();
    f16x8 av[4], bv[4];
    #pragma unroll
    for (int i = 0; i < 4; i++) av[i] = *(const f16x8*)&sA[(wm + i * 16 + lr) * 32 + q4 * 8];
    #pragma unroll
    for (int j = 0; j < 4; j++) bv[j] = *(const f16x8*)&sB[(wn + j * 16 + lr) * 32 + q4 * 8];
    #pragma unroll
    for (int i = 0; i < 4; i++)
      #pragma unroll
      for (int j = 0; j < 4; j++) acc[i][j] = mfma16(av[i], bv[j], acc[i][j]);
  }

  // Epilogue. C/D layout: col = lane&15, row = (lane>>4)*4 + reg.
  #pragma unroll
  for (int i = 0; i < 4; i++) {
    #pragma unroll
    for (int j = 0; j < 4; j++) {
      #pragma unroll
      for (int r = 0; r < 4; r++) {
        const int row = m0 + wm + i * 16 + q4 * 4 + r;
        const int col = n0 + wn + j * 16 + lr;
        float v = acc[i][j][r];
        if constexpr (EPI == EPI_QKV) {
          f16* qb = (f16*)outv;
          const int i3 = col / 768;
          const int rem = col - i3 * 768;
          const int hh = rem >> 6, dd = rem & 63;
          const int bb = row >> 9, ss = row & 511;
          const long bh = bb * 12 + hh;
          if (i3 == 0)      qb[(bh * 512 + ss) * 64 + dd] = (f16)v;           // Q
          else if (i3 == 1) qb[3145728 + (bh * 512 + ss) * 64 + dd] = (f16)v; // K
          else              qb[6291456 + (bh * 64 + dd) * 512 + ss] = (f16)v; // V^T
        } else if constexpr (EPI == EPI_RESID) {
          float* ob = (float*)outv;
          v += bias[col];
          ob[(long)row * ldout + col] = resid[(long)row * ldout + col] + v;
        } else if constexpr (EPI == EPI_GELU) {
          f16* ob = (f16*)outv + (long)pair * strideOut;
          v += bias[(long)wsel * strideBias + col];
          ob[(long)row * ldout + col] = (f16)gelu_exact(v);
        } else {
          f16* ob = (f16*)outv + (long)pair * strideOut;
          v += bias[(long)wsel * strideBias + col];
          ob[(long)row * ldout + col] = (f16)v;
        }
      }
    }
  }
}

// ---------------------------------------------------------------------------
// Fused attention per (b*h, q-tile of 64).
// ---------------------------------------------------------------------------
__global__ __launch_bounds__(256) void attn_kernel(
    const f16* __restrict__ Q, const f16* __restrict__ Kt,
    const f16* __restrict__ Vt, f16* __restrict__ P, f16* __restrict__ AO)
{
  const int bh = blockIdx.x;
  const int qt = blockIdx.y;
  const int t = threadIdx.x;
  const int lane = t & 63, w = t >> 6;
  const int lr = lane & 15, q4 = lane >> 4;
  const int r0 = qt * 64 + w * 16;
  const f16* Qh = Q + (long)bh * 512 * 64;
  const f16* Kh = Kt + (long)bh * 512 * 64;

  f32x4 zero = {0.f, 0.f, 0.f, 0.f};
  f32x4 acc[32];
  #pragma unroll
  for (int i = 0; i < 32; i++) acc[i] = zero;

  #pragma unroll
  for (int kk = 0; kk < 2; kk++) {
    f16x8 a = *(const f16x8*)&Qh[(r0 + lr) * 64 + kk * 32 + q4 * 8];
    #pragma unroll
    for (int nt = 0; nt < 32; nt++) {
      f16x8 b = *(const f16x8*)&Kh[(nt * 16 + lr) * 64 + kk * 32 + q4 * 8];
      acc[nt] = mfma16(a, b, acc[nt]);
    }
  }

  const float cscale = 0.125f * 1.44269504089f;
  f16* Ph = P + (long)bh * 512 * 512;
  #pragma unroll
  for (int r = 0; r < 4; r++) {
    float m = -1e30f;
    #pragma unroll
    for (int nt = 0; nt < 32; nt++) m = fmaxf(m, acc[nt][r]);
    #pragma unroll
    for (int o = 1; o < 16; o <<= 1) m = fmaxf(m, __shfl_xor(m, o, 64));
    float s = 0.f;
    #pragma unroll
    for (int nt = 0; nt < 32; nt++) {
      float e = exp2f((acc[nt][r] - m) * cscale);
      acc[nt][r] = e; s += e;
    }
    #pragma unroll
    for (int o = 1; o < 16; o <<= 1) s += __shfl_xor(s, o, 64);
    const float inv = 1.f / s;
    const int rowg = r0 + q4 * 4 + r;
    #pragma unroll
    for (int nt = 0; nt < 32; nt++)
      Ph[(long)rowg * 512 + nt * 16 + lr] = (f16)(acc[nt][r] * inv);
  }
  __syncthreads();

  const f16* Vh = Vt + (long)bh * 64 * 512;
  f32x4 o4[4];
  #pragma unroll
  for (int i = 0; i < 4; i++) o4[i] = zero;
  #pragma unroll
  for (int kk = 0; kk < 16; kk++) {
    f16x8 a = *(const f16x8*)&Ph[(r0 + lr) * 512 + kk * 32 + q4 * 8];
    #pragma unroll
    for (int nt = 0; nt < 4; nt++) {
      f16x8 b = *(const f16x8*)&Vh[(nt * 16 + lr) * 512 + kk * 32 + q4 * 8];
      o4[nt] = mfma16(a, b, o4[nt]);
    }
  }
  const int b_ = bh / 12, h_ = bh - b_ * 12;
  #pragma unroll
  for (int nt = 0; nt < 4; nt++)
    #pragma unroll
    for (int r = 0; r < 4; r++) {
      const int rowg = r0 + q4 * 4 + r;
      AO[((long)(b_ * 512 + rowg)) * 768 + h_ * 64 + nt * 16 + lr] = (f16)o4[nt][r];
    }
}

// ---------------------------------------------------------------------------
// Router stage 1: parallel partial sums of (x-m)*r over 32-row chunks.
// grid (16 chunks, 8 batches). part[b][c][768].
// ---------------------------------------------------------------------------
__global__ __launch_bounds__(256) void router_reduce(
    const float* __restrict__ x2, const float* __restrict__ lnm,
    const float* __restrict__ lnr, float* __restrict__ part)
{
  const int c = blockIdx.x, b = blockIdx.y, t = threadIdx.x;
  float a0 = 0.f, a1 = 0.f, a2 = 0.f;
  #pragma unroll 4
  for (int s = 0; s < 32; s++) {
    const long base = (long)b * 512 + c * 32 + s;
    const float m = lnm[base], r = lnr[base];
    const float* xr = x2 + base * 768;
    a0 += (xr[t] - m) * r;
    a1 += (xr[t + 256] - m) * r;
    a2 += (xr[t + 512] - m) * r;
  }
  float* pr = part + ((long)b * 16 + c) * 768;
  pr[t] = a0; pr[t + 256] = a1; pr[t + 512] = a2;
}

// ---------------------------------------------------------------------------
// Router stage 2: fold partials -> seq_repr; MLP; softmax; top4 (fp32 exact).
// ---------------------------------------------------------------------------
__global__ __launch_bounds__(256) void router_kernel(
    const float* __restrict__ part, const float* __restrict__ g2,
    const float* __restrict__ b2ln, const float* __restrict__ rw1,
    const float* __restrict__ rb1, const float* __restrict__ rw2,
    const float* __restrict__ rb2, float* __restrict__ wslot,
    int* __restrict__ topkIdx)
{
  __shared__ float seq[768];
  __shared__ float g1[768];
  __shared__ float lg[14];
  const int b = blockIdx.x, t = threadIdx.x;
  float a0 = 0.f, a1 = 0.f, a2 = 0.f;
  const float* pb = part + (long)b * 16 * 768;
  #pragma unroll
  for (int c = 0; c < 16; c++) {
    a0 += pb[c * 768 + t];
    a1 += pb[c * 768 + t + 256];
    a2 += pb[c * 768 + t + 512];
  }
  seq[t]       = a0 * (1.f / 512.f) * g2[t]       + b2ln[t];
  seq[t + 256] = a1 * (1.f / 512.f) * g2[t + 256] + b2ln[t + 256];
  seq[t + 512] = a2 * (1.f / 512.f) * g2[t + 512] + b2ln[t + 512];
  __syncthreads();
  #pragma unroll
  for (int i = 0; i < 3; i++) {
    const int j = t + 256 * i;
    float a = rb1[j];
    for (int d = 0; d < 768; d++) a += seq[d] * rw1[(long)d * 768 + j];
    g1[j] = gelu_exact(a);
  }
  __syncthreads();
  if (t < 14) {
    float a = rb2[t];
    for (int d = 0; d < 768; d++) a += g1[d] * rw2[d * 14 + t];
    lg[t] = a;
  }
  __syncthreads();
  if (t == 0) {
    float mx = -1e30f;
    for (int e = 0; e < 14; e++) mx = fmaxf(mx, lg[e]);
    float p[14], s = 0.f;
    for (int e = 0; e < 14; e++) { p[e] = expf(lg[e] - mx); s += p[e]; }
    for (int e = 0; e < 14; e++) p[e] /= s;
    int idx[4]; float val[4]; bool used[14];
    for (int e = 0; e < 14; e++) used[e] = false;
    for (int k = 0; k < 4; k++) {
      int best = -1; float bv = -1.f;
      for (int e = 0; e < 14; e++)
        if (!used[e] && p[e] > bv) { bv = p[e]; best = e; }
      used[best] = true; idx[k] = best; val[k] = bv;
    }
    const float m2 = val[0];
    float ss = 0.f, e4[4];
    for (int k = 0; k < 4; k++) { e4[k] = expf(val[k] - m2); ss += e4[k]; }
    for (int k = 0; k < 4; k++) {
      wslot[b * 4 + k] = e4[k] / ss;
      topkIdx[b * 4 + k] = idx[k];
    }
  }
}

// ---------------------------------------------------------------------------
// Final combine: out = x2 + sum_k w[b,k]*eo[b,k] + shared_out
// ---------------------------------------------------------------------------
__global__ __launch_bounds__(256) void combine_kernel(
    const float* __restrict__ x2, const f16* __restrict__ shout,
    const f16* __restrict__ eo, const float* __restrict__ wslot,
    float* __restrict__ out)
{
  const long i = (long)blockIdx.x * 256 + threadIdx.x;
  const long b = i / (512L * 768);
  const long loc = i - b * (512L * 768);
  float v = x2[i] + (float)shout[i];
  #pragma unroll
  for (int k = 0; k < 4; k++)
    v += wslot[b * 4 + k] * (float)eo[(b * 4 + k) * (512L * 768) + loc];
  out[i] = v;
}

// ---------------------------------------------------------------------------
// Workspace layout (bytes). Phase A (attention) and Phase B (MoE) overlap.
// ---------------------------------------------------------------------------
static const long OFF_X2    = 0L;                       // 12582912 fp32 x2
static const long OFF_LNM   = 12582912L;
static const long OFF_LNR   = OFF_LNM + 16384L;
static const long OFF_WSLOT = OFF_LNR + 16384L;
static const long OFF_TOPK  = OFF_WSLOT + 256L;
static const long OFF_PART  = OFF_TOPK + 256L;          // 393216 router partials
static const long OFF_A     = 13631488L;                // phase region base
// Phase A
static const long A_H1     = OFF_A;
static const long A_QKVWT  = A_H1 + 6291456L;
static const long A_Q      = A_QKVWT + 3538944L;
static const long A_P      = A_Q + 3L * 6291456L;
static const long A_AO     = A_P + 50331648L;
static const long A_PROJWT = A_AO + 6291456L;
// Phase B (aliases phase A region)
static const long B_H      = OFF_A;
static const long B_EW1T   = B_H + 6291456L;
static const long B_EW2T   = B_EW1T + 33030144L;
static const long B_HID    = B_EW2T + 33030144L;
static const long B_EO     = B_HID + 50331648L;
static const long B_SHW1T  = B_EO + 25165824L;
static const long B_SHW2T  = B_SHW1T + 4718592L;
static const long B_SHOUT  = B_SHW2T + 4718592L;
static const long B_SHID   = B_EW1T;                    // reuse after expert1

extern "C" void kernel_launch(void* const* d_in, const int* in_sizes, int n_in,
                              void* d_out, int out_size, void* d_ws, size_t ws_size,
                              hipStream_t stream) {
  const float* x     = (const float*)d_in[0];
  const float* ln1g  = (const float*)d_in[1];
  const float* ln1b  = (const float*)d_in[2];
  const float* qkvw  = (const float*)d_in[3];
  const float* projw = (const float*)d_in[4];
  const float* projb = (const float*)d_in[5];
  const float* ln2g  = (const float*)d_in[6];
  const float* ln2b  = (const float*)d_in[7];
  const float* rw1   = (const float*)d_in[8];
  const float* rb1   = (const float*)d_in[9];
  const float* rw2   = (const float*)d_in[10];
  const float* rb2   = (const float*)d_in[11];
  const float* ew1   = (const float*)d_in[12];
  const float* eb1   = (const float*)d_in[13];
  const float* ew2   = (const float*)d_in[14];
  const float* eb2   = (const float*)d_in[15];
  const float* shw1  = (const float*)d_in[16];
  const float* shb1  = (const float*)d_in[17];
  const float* shw2  = (const float*)d_in[18];
  const float* shb2  = (const float*)d_in[19];

  char* ws = (char*)d_ws;
  float* x2    = (float*)(ws + OFF_X2);
  float* lnm   = (float*)(ws + OFF_LNM);
  float* lnr   = (float*)(ws + OFF_LNR);
  float* wslot = (float*)(ws + OFF_WSLOT);
  int*   topk  = (int*)(ws + OFF_TOPK);
  float* part  = (float*)(ws + OFF_PART);
  f16* h1     = (f16*)(ws + A_H1);
  f16* qkvwt  = (f16*)(ws + A_QKVWT);
  f16* Qb     = (f16*)(ws + A_Q);
  f16* Kb     = Qb + 3145728;
  f16* Vtb    = Qb + 6291456;
  f16* Pb     = (f16*)(ws + A_P);
  f16* aob    = (f16*)(ws + A_AO);
  f16* projwt = (f16*)(ws + A_PROJWT);
  f16* hbuf   = (f16*)(ws + B_H);
  f16* ew1t   = (f16*)(ws + B_EW1T);
  f16* ew2t   = (f16*)(ws + B_EW2T);
  f16* hid    = (f16*)(ws + B_HID);
  f16* eo     = (f16*)(ws + B_EO);
  f16* shw1t  = (f16*)(ws + B_SHW1T);
  f16* shw2t  = (f16*)(ws + B_SHW2T);
  f16* shout  = (f16*)(ws + B_SHOUT);
  f16* shid   = (f16*)(ws + B_SHID);

  // ---- Phase A: attention ----
  transpose_f16<<<dim3(72, 24, 1), 256, 0, stream>>>(qkvw, qkvwt, 768, 2304);
  transpose_f16<<<dim3(24, 24, 1), 256, 0, stream>>>(projw, projwt, 768, 768);
  ln_kernel<<<4096, 256, 0, stream>>>(x, ln1g, ln1b, h1, lnm, lnr);
  gemm_bt<EPI_QKV><<<dim3(18, 32, 1), 256, 0, stream>>>(
      h1, 768, 0, 0, qkvwt, 0, nullptr, 0, nullptr, (void*)Qb, 0, 0, nullptr);
  attn_kernel<<<dim3(96, 8, 1), 256, 0, stream>>>(Qb, Kb, Vtb, Pb, aob);
  gemm_bt<EPI_RESID><<<dim3(6, 32, 1), 256, 0, stream>>>(
      aob, 768, 0, 0, projwt, 0, projb, 0, nullptr, (void*)x2, 0, 768, x);

  // ---- Phase B: MoE ----
  ln_kernel<<<4096, 256, 0, stream>>>(x2, ln2g, ln2b, hbuf, lnm, lnr);
  router_reduce<<<dim3(16, 8, 1), 256, 0, stream>>>(x2, lnm, lnr, part);
  router_kernel<<<8, 256, 0, stream>>>(part, ln2g, ln2b,
                                       rw1, rb1, rw2, rb2, wslot, topk);
  transpose_f16<<<dim3(48, 24, 14), 256, 0, stream>>>(ew1, ew1t, 768, 1536);
  transpose_f16<<<dim3(24, 48, 14), 256, 0, stream>>>(ew2, ew2t, 1536, 768);
  transpose_f16<<<dim3(96, 24, 1), 256, 0, stream>>>(shw1, shw1t, 768, 3072);
  transpose_f16<<<dim3(24, 96, 1), 256, 0, stream>>>(shw2, shw2t, 3072, 768);
  gemm_bt<EPI_GELU><<<dim3(12, 4, 32), 256, 0, stream>>>(
      hbuf, 768, 512L * 768, 2, ew1t, 1536L * 768, eb1, 1536, topk,
      (void*)hid, 512L * 1536, 1536, nullptr);
  gemm_bt<EPI_PLAIN><<<dim3(6, 4, 32), 256, 0, stream>>>(
      hid, 1536, 512L * 1536, 0, ew2t, 768L * 1536, eb2, 768, topk,
      (void*)eo, 512L * 768, 768, nullptr);
  gemm_bt<EPI_GELU><<<dim3(24, 32, 1), 256, 0, stream>>>(
      hbuf, 768, 0, 0, shw1t, 0, shb1, 0, nullptr, (void*)shid, 0, 3072, nullptr);
  gemm_bt<EPI_PLAIN><<<dim3(6, 32, 1), 256, 0, stream>>>(
      shid, 3072, 0, 0, shw2t, 0, shb2, 0, nullptr, (void*)shout, 0, 768, nullptr);

  combine_kernel<<<12288, 256, 0, stream>>>(x2, shout, eo, wslot, (float*)d_out);
}

// Round 3
// 665.696 us; speedup vs baseline: 1.2737x; 1.1506x over previous
//
#include <hip/hip_runtime.h>
#include <hip/hip_bf16.h>

// ---------------------------------------------------------------------------
// MoE transformer block, MI355X gfx950.
// B=8 S=512 D=768 H=12 dh=64 E=14 K=4 HID=1536 SH=3072
// R3: router MLP parallelized (was 124us latency-bound: 8 blocks x serial
// 768-loop). Now 5 tiny kernels, max serial depth 48 iters, 128-block grid.
// ---------------------------------------------------------------------------

typedef _Float16 f16x8 __attribute__((ext_vector_type(8)));
typedef float f32x4 __attribute__((ext_vector_type(4)));
typedef _Float16 f16;

__device__ __forceinline__ float gelu_exact(float x) {
  return 0.5f * x * (1.0f + erff(x * 0.70710678118654752f));
}

__device__ __forceinline__ f32x4 mfma16(f16x8 a, f16x8 b, f32x4 c) {
  return __builtin_amdgcn_mfma_f32_16x16x32_f16(a, b, c, 0, 0, 0);
}

// async global->LDS, 16B per lane; LDS dst must be wave-uniform base + lane*16
#define ASYNC_CP16(g, l)                                            \
  __builtin_amdgcn_global_load_lds(                                 \
      (const __attribute__((address_space(1))) void*)(g),           \
      (__attribute__((address_space(3))) void*)(l), 16, 0, 0)

// ---------------------------------------------------------------------------
// LayerNorm: fp32 in -> f16 out, saves per-row mean and rstd (for router).
// ---------------------------------------------------------------------------
__global__ __launch_bounds__(256) void ln_kernel(
    const float* __restrict__ x, const float* __restrict__ g,
    const float* __restrict__ bt, f16* __restrict__ out,
    float* __restrict__ mout, float* __restrict__ rout)
{
  const int row = blockIdx.x;
  const float* xr = x + (long)row * 768;
  const int t = threadIdx.x;
  float v0 = xr[t], v1 = xr[t + 256], v2 = xr[t + 512];
  __shared__ float sb[8];
  float s = v0 + v1 + v2;
  #pragma unroll
  for (int o = 32; o > 0; o >>= 1) s += __shfl_xor(s, o, 64);
  const int w = t >> 6;
  if ((t & 63) == 0) sb[w] = s;
  __syncthreads();
  const float mean = (sb[0] + sb[1] + sb[2] + sb[3]) * (1.0f / 768.0f);
  const float d0 = v0 - mean, d1 = v1 - mean, d2 = v2 - mean;
  float q = d0 * d0 + d1 * d1 + d2 * d2;
  #pragma unroll
  for (int o = 32; o > 0; o >>= 1) q += __shfl_xor(q, o, 64);
  if ((t & 63) == 0) sb[4 + w] = q;
  __syncthreads();
  const float var = (sb[4] + sb[5] + sb[6] + sb[7]) * (1.0f / 768.0f);
  const float rstd = rsqrtf(var + 1e-5f);
  f16* orow = out + (long)row * 768;
  orow[t]       = (f16)(d0 * rstd * g[t]       + bt[t]);
  orow[t + 256] = (f16)(d1 * rstd * g[t + 256] + bt[t + 256]);
  orow[t + 512] = (f16)(d2 * rstd * g[t + 512] + bt[t + 512]);
  if (t == 0) { mout[row] = mean; rout[row] = rstd; }
}

// ---------------------------------------------------------------------------
// Transpose + fp32->f16: in [rows][cols] fp32 -> out [cols][rows] f16.
// ---------------------------------------------------------------------------
__global__ __launch_bounds__(256) void transpose_f16(
    const float* __restrict__ in, f16* __restrict__ out, int rows, int cols)
{
  __shared__ float tile[32][33];
  const long boff = (long)blockIdx.z * rows * cols;
  const float* inb = in + boff;
  f16* outb = out + boff;
  const int c0 = blockIdx.x * 32, r0 = blockIdx.y * 32;
  const int tx = threadIdx.x & 31, ty = threadIdx.x >> 5;
  #pragma unroll
  for (int i = 0; i < 32; i += 8)
    tile[ty + i][tx] = inb[(long)(r0 + ty + i) * cols + c0 + tx];
  __syncthreads();
  #pragma unroll
  for (int i = 0; i < 32; i += 8)
    outb[(long)(c0 + ty + i) * rows + r0 + tx] = (f16)tile[tx][ty + i];
}

// ---------------------------------------------------------------------------
// Generic GEMM: C[M,N] = A[M,K] @ W^T   (A f16 row-major, W f16 [N][K]).
// 128x128 tile, BK=32, 4 waves x 64x64. Staging via global_load_lds (m97).
// ---------------------------------------------------------------------------
#define EPI_QKV   0
#define EPI_RESID 1
#define EPI_GELU  2
#define EPI_PLAIN 3

template <int EPI>
__global__ __launch_bounds__(256) void gemm_bt(
    const f16* __restrict__ A, int K, long strideA, int aShift,
    const f16* __restrict__ W, long strideW,
    const float* __restrict__ bias, int strideBias,
    const int* __restrict__ topkIdx,
    void* __restrict__ outv, long strideOut, int ldout,
    const float* __restrict__ resid)
{
  __shared__ f16 sA[128 * 32];
  __shared__ f16 sB[128 * 32];
  const int tid = threadIdx.x;
  const int pair = blockIdx.z;
  const int m0 = blockIdx.y * 128;
  const int n0 = blockIdx.x * 128;
  const f16* Ab = A + ((long)(pair >> aShift)) * strideA;
  const int wsel = topkIdx ? topkIdx[pair] : pair;
  const f16* Wb = W + (long)wsel * strideW;

  const int f = tid * 8;
  const int fr = f >> 5;
  const int fc = f & 31;
  const int lane = tid & 63, wid = tid >> 6;
  const int wm = (wid >> 1) * 64, wn = (wid & 1) * 64;
  const int lr = lane & 15, q4 = lane >> 4;

  f32x4 zero = {0.f, 0.f, 0.f, 0.f};
  f32x4 acc[4][4];
  #pragma unroll
  for (int i = 0; i < 4; i++)
    #pragma unroll
    for (int j = 0; j < 4; j++) acc[i][j] = zero;

  for (int k0 = 0; k0 < K; k0 += 32) {
    __syncthreads();
    ASYNC_CP16(&Ab[(long)(m0 + fr) * K + k0 + fc],      &sA[f]);
    ASYNC_CP16(&Ab[(long)(m0 + fr + 64) * K + k0 + fc], &sA[f + 2048]);
    ASYNC_CP16(&Wb[(long)(n0 + fr) * K + k0 + fc],      &sB[f]);
    ASYNC_CP16(&Wb[(long)(n0 + fr + 64) * K + k0 + fc], &sB[f + 2048]);
    __syncthreads();
    f16x8 av[4], bv[4];
    #pragma unroll
    for (int i = 0; i < 4; i++) av[i] = *(const f16x8*)&sA[(wm + i * 16 + lr) * 32 + q4 * 8];
    #pragma unroll
    for (int j = 0; j < 4; j++) bv[j] = *(const f16x8*)&sB[(wn + j * 16 + lr) * 32 + q4 * 8];
    #pragma unroll
    for (int i = 0; i < 4; i++)
      #pragma unroll
      for (int j = 0; j < 4; j++) acc[i][j] = mfma16(av[i], bv[j], acc[i][j]);
  }

  // Epilogue. C/D layout: col = lane&15, row = (lane>>4)*4 + reg.
  #pragma unroll
  for (int i = 0; i < 4; i++) {
    #pragma unroll
    for (int j = 0; j < 4; j++) {
      #pragma unroll
      for (int r = 0; r < 4; r++) {
        const int row = m0 + wm + i * 16 + q4 * 4 + r;
        const int col = n0 + wn + j * 16 + lr;
        float v = acc[i][j][r];
        if constexpr (EPI == EPI_QKV) {
          f16* qb = (f16*)outv;
          const int i3 = col / 768;
          const int rem = col - i3 * 768;
          const int hh = rem >> 6, dd = rem & 63;
          const int bb = row >> 9, ss = row & 511;
          const long bh = bb * 12 + hh;
          if (i3 == 0)      qb[(bh * 512 + ss) * 64 + dd] = (f16)v;           // Q
          else if (i3 == 1) qb[3145728 + (bh * 512 + ss) * 64 + dd] = (f16)v; // K
          else              qb[6291456 + (bh * 64 + dd) * 512 + ss] = (f16)v; // V^T
        } else if constexpr (EPI == EPI_RESID) {
          float* ob = (float*)outv;
          v += bias[col];
          ob[(long)row * ldout + col] = resid[(long)row * ldout + col] + v;
        } else if constexpr (EPI == EPI_GELU) {
          f16* ob = (f16*)outv + (long)pair * strideOut;
          v += bias[(long)wsel * strideBias + col];
          ob[(long)row * ldout + col] = (f16)gelu_exact(v);
        } else {
          f16* ob = (f16*)outv + (long)pair * strideOut;
          v += bias[(long)wsel * strideBias + col];
          ob[(long)row * ldout + col] = (f16)v;
        }
      }
    }
  }
}

// ---------------------------------------------------------------------------
// Fused attention per (b*h, q-tile of 64).
// ---------------------------------------------------------------------------
__global__ __launch_bounds__(256) void attn_kernel(
    const f16* __restrict__ Q, const f16* __restrict__ Kt,
    const f16* __restrict__ Vt, f16* __restrict__ P, f16* __restrict__ AO)
{
  const int bh = blockIdx.x;
  const int qt = blockIdx.y;
  const int t = threadIdx.x;
  const int lane = t & 63, w = t >> 6;
  const int lr = lane & 15, q4 = lane >> 4;
  const int r0 = qt * 64 + w * 16;
  const f16* Qh = Q + (long)bh * 512 * 64;
  const f16* Kh = Kt + (long)bh * 512 * 64;

  f32x4 zero = {0.f, 0.f, 0.f, 0.f};
  f32x4 acc[32];
  #pragma unroll
  for (int i = 0; i < 32; i++) acc[i] = zero;

  #pragma unroll
  for (int kk = 0; kk < 2; kk++) {
    f16x8 a = *(const f16x8*)&Qh[(r0 + lr) * 64 + kk * 32 + q4 * 8];
    #pragma unroll
    for (int nt = 0; nt < 32; nt++) {
      f16x8 b = *(const f16x8*)&Kh[(nt * 16 + lr) * 64 + kk * 32 + q4 * 8];
      acc[nt] = mfma16(a, b, acc[nt]);
    }
  }

  const float cscale = 0.125f * 1.44269504089f;
  f16* Ph = P + (long)bh * 512 * 512;
  #pragma unroll
  for (int r = 0; r < 4; r++) {
    float m = -1e30f;
    #pragma unroll
    for (int nt = 0; nt < 32; nt++) m = fmaxf(m, acc[nt][r]);
    #pragma unroll
    for (int o = 1; o < 16; o <<= 1) m = fmaxf(m, __shfl_xor(m, o, 64));
    float s = 0.f;
    #pragma unroll
    for (int nt = 0; nt < 32; nt++) {
      float e = exp2f((acc[nt][r] - m) * cscale);
      acc[nt][r] = e; s += e;
    }
    #pragma unroll
    for (int o = 1; o < 16; o <<= 1) s += __shfl_xor(s, o, 64);
    const float inv = 1.f / s;
    const int rowg = r0 + q4 * 4 + r;
    #pragma unroll
    for (int nt = 0; nt < 32; nt++)
      Ph[(long)rowg * 512 + nt * 16 + lr] = (f16)(acc[nt][r] * inv);
  }
  __syncthreads();

  const f16* Vh = Vt + (long)bh * 64 * 512;
  f32x4 o4[4];
  #pragma unroll
  for (int i = 0; i < 4; i++) o4[i] = zero;
  #pragma unroll
  for (int kk = 0; kk < 16; kk++) {
    f16x8 a = *(const f16x8*)&Ph[(r0 + lr) * 512 + kk * 32 + q4 * 8];
    #pragma unroll
    for (int nt = 0; nt < 4; nt++) {
      f16x8 b = *(const f16x8*)&Vh[(nt * 16 + lr) * 512 + kk * 32 + q4 * 8];
      o4[nt] = mfma16(a, b, o4[nt]);
    }
  }
  const int b_ = bh / 12, h_ = bh - b_ * 12;
  #pragma unroll
  for (int nt = 0; nt < 4; nt++)
    #pragma unroll
    for (int r = 0; r < 4; r++) {
      const int rowg = r0 + q4 * 4 + r;
      AO[((long)(b_ * 512 + rowg)) * 768 + h_ * 64 + nt * 16 + lr] = (f16)o4[nt][r];
    }
}

// ---------------------------------------------------------------------------
// Router stage 1: partial sums of (x-m)*r over 32-row chunks. part[b][c][768].
// ---------------------------------------------------------------------------
__global__ __launch_bounds__(256) void router_reduce(
    const float* __restrict__ x2, const float* __restrict__ lnm,
    const float* __restrict__ lnr, float* __restrict__ part)
{
  const int c = blockIdx.x, b = blockIdx.y, t = threadIdx.x;
  float a0 = 0.f, a1 = 0.f, a2 = 0.f;
  #pragma unroll 4
  for (int s = 0; s < 32; s++) {
    const long base = (long)b * 512 + c * 32 + s;
    const float m = lnm[base], r = lnr[base];
    const float* xr = x2 + base * 768;
    a0 += (xr[t] - m) * r;
    a1 += (xr[t + 256] - m) * r;
    a2 += (xr[t + 512] - m) * r;
  }
  float* pr = part + ((long)b * 16 + c) * 768;
  pr[t] = a0; pr[t + 256] = a1; pr[t + 512] = a2;
}

// ---------------------------------------------------------------------------
// Router stage 2: fold partials -> seq_repr (fp32, global).
// ---------------------------------------------------------------------------
__global__ __launch_bounds__(256) void router_seq(
    const float* __restrict__ part, const float* __restrict__ g2,
    const float* __restrict__ b2ln, float* __restrict__ seqg)
{
  const int b = blockIdx.x, t = threadIdx.x;
  const float* pb = part + (long)b * 16 * 768;
  #pragma unroll
  for (int i = 0; i < 3; i++) {
    const int j = t + 256 * i;
    float a = 0.f;
    #pragma unroll
    for (int c = 0; c < 16; c++) a += pb[c * 768 + j];
    seqg[b * 768 + j] = a * (1.f / 512.f) * g2[j] + b2ln[j];
  }
}

// ---------------------------------------------------------------------------
// Router stage 3: MLP1 partials. Block (dchunk c of 48, batch b):
// pmlp[b][c][j] = sum_{d in chunk} seq[d] * rw1[d][j].  j coalesced over t.
// ---------------------------------------------------------------------------
__global__ __launch_bounds__(256) void router_mlp1(
    const float* __restrict__ seqg, const float* __restrict__ rw1,
    float* __restrict__ pmlp)
{
  const int c = blockIdx.x, b = blockIdx.y, t = threadIdx.x;
  const float* sq = seqg + b * 768 + c * 48;
  float a0 = 0.f, a1 = 0.f, a2 = 0.f;
  #pragma unroll 8
  for (int d = 0; d < 48; d++) {
    const float s = sq[d];             // wave-uniform (scalar load)
    const float* wr = rw1 + (long)(c * 48 + d) * 768;
    a0 += s * wr[t];
    a1 += s * wr[t + 256];
    a2 += s * wr[t + 512];
  }
  float* pr = pmlp + ((long)b * 16 + c) * 768;
  pr[t] = a0; pr[t + 256] = a1; pr[t + 512] = a2;
}

// ---------------------------------------------------------------------------
// Router stage 4: fold MLP1 partials + bias + gelu -> g1g.
// ---------------------------------------------------------------------------
__global__ __launch_bounds__(256) void router_fold(
    const float* __restrict__ pmlp, const float* __restrict__ rb1,
    float* __restrict__ g1g)
{
  const int b = blockIdx.x, t = threadIdx.x;
  const float* pb = pmlp + (long)b * 16 * 768;
  #pragma unroll
  for (int i = 0; i < 3; i++) {
    const int j = t + 256 * i;
    float a = rb1[j];
    #pragma unroll
    for (int c = 0; c < 16; c++) a += pb[c * 768 + j];
    g1g[b * 768 + j] = gelu_exact(a);
  }
}

// ---------------------------------------------------------------------------
// Router stage 5: logits = g1 @ rw2 + rb2; softmax; top4; renorm (fp32 exact).
// Block per batch; 16 threads per expert for the dot.
// ---------------------------------------------------------------------------
__global__ __launch_bounds__(256) void router_top(
    const float* __restrict__ g1g, const float* __restrict__ rw2,
    const float* __restrict__ rb2, float* __restrict__ wslot,
    int* __restrict__ topkIdx)
{
  __shared__ float lg[14];
  const int b = blockIdx.x, t = threadIdx.x;
  const int e = t >> 4, sub = t & 15;
  if (e < 14) {
    float a = 0.f;
    #pragma unroll
    for (int i = 0; i < 48; i++) {
      const int d = sub + 16 * i;
      a += g1g[b * 768 + d] * rw2[d * 14 + e];
    }
    #pragma unroll
    for (int o = 1; o < 16; o <<= 1) a += __shfl_xor(a, o, 64);
    if (sub == 0) lg[e] = a + rb2[e];
  }
  __syncthreads();
  if (t == 0) {
    float mx = -1e30f;
    for (int ee = 0; ee < 14; ee++) mx = fmaxf(mx, lg[ee]);
    float p[14], s = 0.f;
    for (int ee = 0; ee < 14; ee++) { p[ee] = expf(lg[ee] - mx); s += p[ee]; }
    for (int ee = 0; ee < 14; ee++) p[ee] /= s;
    int idx[4]; float val[4]; bool used[14];
    for (int ee = 0; ee < 14; ee++) used[ee] = false;
    for (int k = 0; k < 4; k++) {
      int best = -1; float bv = -1.f;
      for (int ee = 0; ee < 14; ee++)
        if (!used[ee] && p[ee] > bv) { bv = p[ee]; best = ee; }
      used[best] = true; idx[k] = best; val[k] = bv;
    }
    const float m2 = val[0];
    float ss = 0.f, e4[4];
    for (int k = 0; k < 4; k++) { e4[k] = expf(val[k] - m2); ss += e4[k]; }
    for (int k = 0; k < 4; k++) {
      wslot[b * 4 + k] = e4[k] / ss;
      topkIdx[b * 4 + k] = idx[k];
    }
  }
}

// ---------------------------------------------------------------------------
// Final combine: out = x2 + sum_k w[b,k]*eo[b,k] + shared_out
// ---------------------------------------------------------------------------
__global__ __launch_bounds__(256) void combine_kernel(
    const float* __restrict__ x2, const f16* __restrict__ shout,
    const f16* __restrict__ eo, const float* __restrict__ wslot,
    float* __restrict__ out)
{
  const long i = (long)blockIdx.x * 256 + threadIdx.x;
  const long b = i / (512L * 768);
  const long loc = i - b * (512L * 768);
  float v = x2[i] + (float)shout[i];
  #pragma unroll
  for (int k = 0; k < 4; k++)
    v += wslot[b * 4 + k] * (float)eo[(b * 4 + k) * (512L * 768) + loc];
  out[i] = v;
}

// ---------------------------------------------------------------------------
// Workspace layout (bytes).
// ---------------------------------------------------------------------------
static const long OFF_X2    = 0L;                       // 12582912 fp32 x2
static const long OFF_LNM   = 12582912L;
static const long OFF_LNR   = OFF_LNM + 16384L;
static const long OFF_WSLOT = OFF_LNR + 16384L;
static const long OFF_TOPK  = OFF_WSLOT + 256L;
static const long OFF_PART  = OFF_TOPK + 256L;          // 393216
static const long OFF_SEQG  = OFF_PART + 393216L;       // 24576
static const long OFF_PMLP  = OFF_SEQG + 24576L;        // 393216
static const long OFF_G1G   = OFF_PMLP + 393216L;       // 24576 (ends 13451776)
static const long OFF_A     = 13631488L;                // phase region base
// Phase A
static const long A_H1     = OFF_A;
static const long A_QKVWT  = A_H1 + 6291456L;
static const long A_Q      = A_QKVWT + 3538944L;
static const long A_P      = A_Q + 3L * 6291456L;
static const long A_AO     = A_P + 50331648L;
static const long A_PROJWT = A_AO + 6291456L;
// Phase B (aliases phase A region)
static const long B_H      = OFF_A;
static const long B_EW1T   = B_H + 6291456L;
static const long B_EW2T   = B_EW1T + 33030144L;
static const long B_HID    = B_EW2T + 33030144L;
static const long B_EO     = B_HID + 50331648L;
static const long B_SHW1T  = B_EO + 25165824L;
static const long B_SHW2T  = B_SHW1T + 4718592L;
static const long B_SHOUT  = B_SHW2T + 4718592L;
static const long B_SHID   = B_EW1T;                    // reuse after expert1

extern "C" void kernel_launch(void* const* d_in, const int* in_sizes, int n_in,
                              void* d_out, int out_size, void* d_ws, size_t ws_size,
                              hipStream_t stream) {
  const float* x     = (const float*)d_in[0];
  const float* ln1g  = (const float*)d_in[1];
  const float* ln1b  = (const float*)d_in[2];
  const float* qkvw  = (const float*)d_in[3];
  const float* projw = (const float*)d_in[4];
  const float* projb = (const float*)d_in[5];
  const float* ln2g  = (const float*)d_in[6];
  const float* ln2b  = (const float*)d_in[7];
  const float* rw1   = (const float*)d_in[8];
  const float* rb1   = (const float*)d_in[9];
  const float* rw2   = (const float*)d_in[10];
  const float* rb2   = (const float*)d_in[11];
  const float* ew1   = (const float*)d_in[12];
  const float* eb1   = (const float*)d_in[13];
  const float* ew2   = (const float*)d_in[14];
  const float* eb2   = (const float*)d_in[15];
  const float* shw1  = (const float*)d_in[16];
  const float* shb1  = (const float*)d_in[17];
  const float* shw2  = (const float*)d_in[18];
  const float* shb2  = (const float*)d_in[19];

  char* ws = (char*)d_ws;
  float* x2    = (float*)(ws + OFF_X2);
  float* lnm   = (float*)(ws + OFF_LNM);
  float* lnr   = (float*)(ws + OFF_LNR);
  float* wslot = (float*)(ws + OFF_WSLOT);
  int*   topk  = (int*)(ws + OFF_TOPK);
  float* part  = (float*)(ws + OFF_PART);
  float* seqg  = (float*)(ws + OFF_SEQG);
  float* pmlp  = (float*)(ws + OFF_PMLP);
  float* g1g   = (float*)(ws + OFF_G1G);
  f16* h1     = (f16*)(ws + A_H1);
  f16* qkvwt  = (f16*)(ws + A_QKVWT);
  f16* Qb     = (f16*)(ws + A_Q);
  f16* Kb     = Qb + 3145728;
  f16* Vtb    = Qb + 6291456;
  f16* Pb     = (f16*)(ws + A_P);
  f16* aob    = (f16*)(ws + A_AO);
  f16* projwt = (f16*)(ws + A_PROJWT);
  f16* hbuf   = (f16*)(ws + B_H);
  f16* ew1t   = (f16*)(ws + B_EW1T);
  f16* ew2t   = (f16*)(ws + B_EW2T);
  f16* hid    = (f16*)(ws + B_HID);
  f16* eo     = (f16*)(ws + B_EO);
  f16* shw1t  = (f16*)(ws + B_SHW1T);
  f16* shw2t  = (f16*)(ws + B_SHW2T);
  f16* shout  = (f16*)(ws + B_SHOUT);
  f16* shid   = (f16*)(ws + B_SHID);

  // ---- Phase A: attention ----
  transpose_f16<<<dim3(72, 24, 1), 256, 0, stream>>>(qkvw, qkvwt, 768, 2304);
  transpose_f16<<<dim3(24, 24, 1), 256, 0, stream>>>(projw, projwt, 768, 768);
  ln_kernel<<<4096, 256, 0, stream>>>(x, ln1g, ln1b, h1, lnm, lnr);
  gemm_bt<EPI_QKV><<<dim3(18, 32, 1), 256, 0, stream>>>(
      h1, 768, 0, 0, qkvwt, 0, nullptr, 0, nullptr, (void*)Qb, 0, 0, nullptr);
  attn_kernel<<<dim3(96, 8, 1), 256, 0, stream>>>(Qb, Kb, Vtb, Pb, aob);
  gemm_bt<EPI_RESID><<<dim3(6, 32, 1), 256, 0, stream>>>(
      aob, 768, 0, 0, projwt, 0, projb, 0, nullptr, (void*)x2, 0, 768, x);

  // ---- Phase B: MoE ----
  ln_kernel<<<4096, 256, 0, stream>>>(x2, ln2g, ln2b, hbuf, lnm, lnr);
  router_reduce<<<dim3(16, 8, 1), 256, 0, stream>>>(x2, lnm, lnr, part);
  router_seq<<<8, 256, 0, stream>>>(part, ln2g, ln2b, seqg);
  router_mlp1<<<dim3(16, 8, 1), 256, 0, stream>>>(seqg, rw1, pmlp);
  router_fold<<<8, 256, 0, stream>>>(pmlp, rb1, g1g);
  router_top<<<8, 256, 0, stream>>>(g1g, rw2, rb2, wslot, topk);
  transpose_f16<<<dim3(48, 24, 14), 256, 0, stream>>>(ew1, ew1t, 768, 1536);
  transpose_f16<<<dim3(24, 48, 14), 256, 0, stream>>>(ew2, ew2t, 1536, 768);
  transpose_f16<<<dim3(96, 24, 1), 256, 0, stream>>>(shw1, shw1t, 768, 3072);
  transpose_f16<<<dim3(24, 96, 1), 256, 0, stream>>>(shw2, shw2t, 3072, 768);
  gemm_bt<EPI_GELU><<<dim3(12, 4, 32), 256, 0, stream>>>(
      hbuf, 768, 512L * 768, 2, ew1t, 1536L * 768, eb1, 1536, topk,
      (void*)hid, 512L * 1536, 1536, nullptr);
  gemm_bt<EPI_PLAIN><<<dim3(6, 4, 32), 256, 0, stream>>>(
      hid, 1536, 512L * 1536, 0, ew2t, 768L * 1536, eb2, 768, topk,
      (void*)eo, 512L * 768, 768, nullptr);
  gemm_bt<EPI_GELU><<<dim3(24, 32, 1), 256, 0, stream>>>(
      hbuf, 768, 0, 0, shw1t, 0, shb1, 0, nullptr, (void*)shid, 0, 3072, nullptr);
  gemm_bt<EPI_PLAIN><<<dim3(6, 32, 1), 256, 0, stream>>>(
      shid, 3072, 0, 0, shw2t, 0, shb2, 0, nullptr, (void*)shout, 0, 768, nullptr);

  combine_kernel<<<12288, 256, 0, stream>>>(x2, shout, eo, wslot, (float*)d_out);
}